// Round 1
// baseline (1195.336 us; speedup 1.0000x reference)
//
#include <hip/hip_runtime.h>
#include <hip/hip_bf16.h>

#define NN 50000
#define EE 800000
#define IN_DIM 64
#define DS_DIM 32
#define HOUT_DIM 64

__device__ __forceinline__ float fast_tanh(float x) {
    float xc = fminf(fmaxf(x, -15.f), 15.f);
    float e2 = __expf(2.f * xc);
    return __fdividef(e2 - 1.f, e2 + 1.f);
}

__device__ __forceinline__ void atomAddF(float* p, float v) {
#if defined(__AMDGCN__)
    unsafeAtomicAdd(p, v);
#else
    atomicAdd(p, v);
#endif
}

// K1: per-node encoders. thread = (node, f) with f in [0,128):
//   f in [0,32):   hK  = p @ WencK  + bencK      (p = x[:,32:64])
//   f in [32,64):  h1  = q @ WencP1 + bencP1     (q = x[:,0:32])
//   f in [64,96):  h2  = q @ WencP2 + bencP2
//   f in [96,128): DxU = (x @ WD + bD)[:,32:64]
__global__ void k1_encoders(const float* __restrict__ x,
                            const float* __restrict__ WencK, const float* __restrict__ bencK,
                            const float* __restrict__ WencP1, const float* __restrict__ bencP1,
                            const float* __restrict__ WencP2, const float* __restrict__ bencP2,
                            const float* __restrict__ WD, const float* __restrict__ bD,
                            float* __restrict__ hK, float* __restrict__ h1,
                            float* __restrict__ h2, float* __restrict__ DxU) {
    int tid = blockIdx.x * blockDim.x + threadIdx.x;
    int n = tid >> 7;
    int f = tid & 127;
    if (n >= NN) return;
    const float* xr = x + (size_t)n * IN_DIM;
    int j = f & 31;
    if (f < 32) {
        float acc = bencK[j];
        #pragma unroll
        for (int k = 0; k < 32; k++) acc = fmaf(xr[32 + k], WencK[k * 32 + j], acc);
        hK[(size_t)n * 32 + j] = acc;
    } else if (f < 64) {
        float acc = bencP1[j];
        #pragma unroll
        for (int k = 0; k < 32; k++) acc = fmaf(xr[k], WencP1[k * 32 + j], acc);
        h1[(size_t)n * 32 + j] = acc;
    } else if (f < 96) {
        float acc = bencP2[j];
        #pragma unroll
        for (int k = 0; k < 32; k++) acc = fmaf(xr[k], WencP2[k * 32 + j], acc);
        h2[(size_t)n * 32 + j] = acc;
    } else {
        float acc = bD[32 + j];
        #pragma unroll
        for (int k = 0; k < 64; k++) acc = fmaf(xr[k], WD[k * 64 + 32 + j], acc);
        DxU[(size_t)n * 32 + j] = acc;
    }
}

// K2: edge scatter of hK and DxU into dst accumulators. thread = (edge, f<32).
__global__ void k2_scatter1(const int* __restrict__ src, const int* __restrict__ dst,
                            const float* __restrict__ hK, const float* __restrict__ DxU,
                            float* __restrict__ hK_agg, float* __restrict__ d_agg) {
    int tid = blockIdx.x * blockDim.x + threadIdx.x;
    int e = tid >> 5;
    int f = tid & 31;
    if (e >= EE) return;
    int s = src[e], d = dst[e];
    atomAddF(&hK_agg[(size_t)d * 32 + f], hK[(size_t)s * 32 + f]);
    atomAddF(&d_agg[(size_t)d * 32 + f], DxU[(size_t)s * 32 + f]);
}

// K3: E_node = mlp3(hK_agg). node-per-thread, fully unrolled, weights via s_load.
__global__ void k3_node_mlp(const float* __restrict__ hK_agg,
                            const float* __restrict__ WK1, const float* __restrict__ bK1,
                            const float* __restrict__ WK2, const float* __restrict__ bK2,
                            const float* __restrict__ WK3, const float* __restrict__ bK3,
                            float* __restrict__ Enode) {
    int n = blockIdx.x * blockDim.x + threadIdx.x;
    if (n >= NN) return;
    float in[32];
    const float4* iv = reinterpret_cast<const float4*>(hK_agg + (size_t)n * 32);
    #pragma unroll
    for (int i = 0; i < 8; i++) {
        float4 v = iv[i];
        in[4 * i + 0] = v.x; in[4 * i + 1] = v.y; in[4 * i + 2] = v.z; in[4 * i + 3] = v.w;
    }
    float t1[64];
    #pragma unroll
    for (int j = 0; j < 64; j++) t1[j] = bK1[j];
    #pragma unroll
    for (int k = 0; k < 32; k++) {
        float s0 = in[k];
        #pragma unroll
        for (int j = 0; j < 64; j++) t1[j] = fmaf(s0, WK1[k * 64 + j], t1[j]);
    }
    #pragma unroll
    for (int j = 0; j < 64; j++) t1[j] = fast_tanh(t1[j]);
    float t2[64];
    #pragma unroll
    for (int j = 0; j < 64; j++) t2[j] = bK2[j];
    #pragma unroll
    for (int k = 0; k < 64; k++) {
        float s0 = t1[k];
        #pragma unroll
        for (int j = 0; j < 64; j++) t2[j] = fmaf(s0, WK2[k * 64 + j], t2[j]);
    }
    #pragma unroll
    for (int j = 0; j < 64; j++) t2[j] = fmaxf(t2[j], 0.f);
    float t3[64];
    #pragma unroll
    for (int j = 0; j < 64; j++) t3[j] = bK3[j];
    #pragma unroll
    for (int k = 0; k < 64; k++) {
        float s0 = t2[k];
        #pragma unroll
        for (int j = 0; j < 64; j++) t3[j] = fmaf(s0, WK3[k * 64 + j], t3[j]);
    }
    float4* ov = reinterpret_cast<float4*>(Enode + (size_t)n * 64);
    #pragma unroll
    for (int i = 0; i < 16; i++) {
        float4 v; v.x = t3[4 * i + 0]; v.y = t3[4 * i + 1]; v.z = t3[4 * i + 2]; v.w = t3[4 * i + 3];
        ov[i] = v;
    }
}

// K4: the big one. edge-per-lane MLP (E_edge), then LDS transpose so that the
// E_node gather and the E_new atomic scatter are 256B-coalesced per edge.
__global__ void __launch_bounds__(64) k4_edge(const int* __restrict__ src, const int* __restrict__ dst,
                                              const float* __restrict__ h1, const float* __restrict__ h2,
                                              const float* __restrict__ Enode, float* __restrict__ Enew,
                                              const float* __restrict__ WU1, const float* __restrict__ bU1,
                                              const float* __restrict__ WU2, const float* __restrict__ bU2,
                                              const float* __restrict__ WU3, const float* __restrict__ bU3) {
    __shared__ float xch[64][65];
    int lane = threadIdx.x;
    int e = blockIdx.x * 64 + lane;   // EE == 12500*64 exactly, no tail
    int s = src[e], d = dst[e];
    float ev[32];
    {
        const float4* a4 = reinterpret_cast<const float4*>(h1 + (size_t)s * 32);
        const float4* b4 = reinterpret_cast<const float4*>(h2 + (size_t)d * 32);
        #pragma unroll
        for (int i = 0; i < 8; i++) {
            float4 a = a4[i]; float4 b = b4[i];
            ev[4 * i + 0] = a.x + b.x;
            ev[4 * i + 1] = a.y + b.y;
            ev[4 * i + 2] = a.z + b.z;
            ev[4 * i + 3] = a.w + b.w;
        }
    }
    float t1[64];
    #pragma unroll
    for (int j = 0; j < 64; j++) t1[j] = bU1[j];
    #pragma unroll
    for (int k = 0; k < 32; k++) {
        float s0 = ev[k];
        #pragma unroll
        for (int j = 0; j < 64; j++) t1[j] = fmaf(s0, WU1[k * 64 + j], t1[j]);
    }
    #pragma unroll
    for (int j = 0; j < 64; j++) t1[j] = fast_tanh(t1[j]);
    float t2[64];
    #pragma unroll
    for (int j = 0; j < 64; j++) t2[j] = bU2[j];
    #pragma unroll
    for (int k = 0; k < 64; k++) {
        float s0 = t1[k];
        #pragma unroll
        for (int j = 0; j < 64; j++) t2[j] = fmaf(s0, WU2[k * 64 + j], t2[j]);
    }
    #pragma unroll
    for (int j = 0; j < 64; j++) t2[j] = fmaxf(t2[j], 0.f);
    float t3[64];
    #pragma unroll
    for (int j = 0; j < 64; j++) t3[j] = bU3[j];
    #pragma unroll
    for (int k = 0; k < 64; k++) {
        float s0 = t2[k];
        #pragma unroll
        for (int j = 0; j < 64; j++) t3[j] = fmaf(s0, WU3[k * 64 + j], t3[j]);
    }
    // transpose E_edge rows into LDS: xch[edge_local][feature]
    #pragma unroll
    for (int j = 0; j < 64; j++) xch[lane][j] = t3[j];
    __syncthreads();
    // per local edge: coalesced E_node gather + coalesced atomic scatter
    #pragma unroll 8
    for (int el = 0; el < 64; el++) {
        int ss = __shfl(s, el);
        int dd = __shfl(d, el);
        float en = Enode[(size_t)ss * 64 + lane];
        float val = xch[el][lane] * en;
        atomAddF(&Enew[(size_t)dd * 64 + lane], val);
    }
}

// K5: dH = E_new @ WH + bH ; out[:, :32] = dH[:,32:], out[:,32:] = -dH[:,:32] - d_agg
__global__ void k5_out(const float* __restrict__ Enew, const float* __restrict__ d_agg,
                       const float* __restrict__ WH, const float* __restrict__ bH,
                       float* __restrict__ out) {
    int tid = blockIdx.x * blockDim.x + threadIdx.x;
    int n = tid >> 6;
    int j = tid & 63;
    if (n >= NN) return;
    const float* er = Enew + (size_t)n * 64;
    int jj = (j < 32) ? (j + 32) : (j - 32);
    float acc = bH[jj];
    #pragma unroll
    for (int k = 0; k < 64; k++) acc = fmaf(er[k], WH[k * 64 + jj], acc);
    float val;
    if (j < 32) {
        val = acc;
    } else {
        val = -acc - d_agg[(size_t)n * 32 + (j - 32)];
    }
    out[tid] = val;
}

extern "C" void kernel_launch(void* const* d_in, const int* in_sizes, int n_in,
                              void* d_out, int out_size, void* d_ws, size_t ws_size,
                              hipStream_t stream) {
    const float* x      = (const float*)d_in[0];
    const int*   src    = (const int*)d_in[1];
    const int*   dst    = (const int*)d_in[2];
    const float* WencK  = (const float*)d_in[3];
    const float* bencK  = (const float*)d_in[4];
    const float* WencP1 = (const float*)d_in[5];
    const float* bencP1 = (const float*)d_in[6];
    const float* WencP2 = (const float*)d_in[7];
    const float* bencP2 = (const float*)d_in[8];
    const float* WK1    = (const float*)d_in[9];
    const float* bK1    = (const float*)d_in[10];
    const float* WK2    = (const float*)d_in[11];
    const float* bK2    = (const float*)d_in[12];
    const float* WK3    = (const float*)d_in[13];
    const float* bK3    = (const float*)d_in[14];
    const float* WU1    = (const float*)d_in[15];
    const float* bU1    = (const float*)d_in[16];
    const float* WU2    = (const float*)d_in[17];
    const float* bU2    = (const float*)d_in[18];
    const float* WU3    = (const float*)d_in[19];
    const float* bU3    = (const float*)d_in[20];
    const float* WH     = (const float*)d_in[21];
    const float* bH     = (const float*)d_in[22];
    const float* WD     = (const float*)d_in[23];
    const float* bD     = (const float*)d_in[24];
    float* out = (float*)d_out;

    float* ws = (float*)d_ws;
    // layout (floats): [hK_agg N*32 | d_agg N*32 | Enew N*64 | hK N*32 | h1 N*32 | h2 N*32 | DxU N*32 | Enode N*64]
    float* hK_agg = ws;
    float* d_agg  = ws + (size_t)NN * 32;
    float* Enew   = ws + (size_t)NN * 64;
    float* hK     = ws + (size_t)NN * 128;
    float* h1     = ws + (size_t)NN * 160;
    float* h2     = ws + (size_t)NN * 192;
    float* DxU    = ws + (size_t)NN * 224;
    float* Enode  = ws + (size_t)NN * 256;   // ends at NN*320 floats = 64 MB
    if (ws_size < (size_t)NN * 320 * sizeof(float)) return;

    // zero the three accumulators (contiguous, N*128 floats)
    hipMemsetAsync(ws, 0, (size_t)NN * 128 * sizeof(float), stream);

    k1_encoders<<<(NN * 128 + 255) / 256, 256, 0, stream>>>(
        x, WencK, bencK, WencP1, bencP1, WencP2, bencP2, WD, bD, hK, h1, h2, DxU);
    k2_scatter1<<<(EE * 32 + 255) / 256, 256, 0, stream>>>(src, dst, hK, DxU, hK_agg, d_agg);
    k3_node_mlp<<<(NN + 63) / 64, 64, 0, stream>>>(hK_agg, WK1, bK1, WK2, bK2, WK3, bK3, Enode);
    k4_edge<<<EE / 64, 64, 0, stream>>>(src, dst, h1, h2, Enode, Enew, WU1, bU1, WU2, bU2, WU3, bU3);
    k5_out<<<(NN * 64 + 255) / 256, 256, 0, stream>>>(Enew, d_agg, WH, bH, out);
}

// Round 2
// 676.563 us; speedup vs baseline: 1.7668x; 1.7668x over previous
//
#include <hip/hip_runtime.h>
#include <hip/hip_bf16.h>

#define NN 50000
#define EE 800000
#define IN_DIM 64
#define DS_DIM 32
#define HOUT_DIM 64

typedef __attribute__((ext_vector_type(8))) short bf16x8;
typedef __attribute__((ext_vector_type(4))) float f32x4;

__device__ __forceinline__ float fast_tanh(float x) {
    float xc = fminf(fmaxf(x, -15.f), 15.f);
    float e2 = __expf(2.f * xc);
    return __fdividef(e2 - 1.f, e2 + 1.f);
}

__device__ __forceinline__ void atomAddF(float* p, float v) {
#if defined(__AMDGCN__)
    unsafeAtomicAdd(p, v);
#else
    atomicAdd(p, v);
#endif
}

__device__ __forceinline__ short f2b(float f) {
    union { __hip_bfloat16 h; short s; } u;
    u.h = __float2bfloat16(f);
    return u.s;
}

// K1: per-node encoders. thread = (node, f) with f in [0,128).
__global__ void k1_encoders(const float* __restrict__ x,
                            const float* __restrict__ WencK, const float* __restrict__ bencK,
                            const float* __restrict__ WencP1, const float* __restrict__ bencP1,
                            const float* __restrict__ WencP2, const float* __restrict__ bencP2,
                            const float* __restrict__ WD, const float* __restrict__ bD,
                            float* __restrict__ hK, float* __restrict__ h1,
                            float* __restrict__ h2, float* __restrict__ DxU) {
    int tid = blockIdx.x * blockDim.x + threadIdx.x;
    int n = tid >> 7;
    int f = tid & 127;
    if (n >= NN) return;
    const float* xr = x + (size_t)n * IN_DIM;
    int j = f & 31;
    if (f < 32) {
        float acc = bencK[j];
        #pragma unroll
        for (int k = 0; k < 32; k++) acc = fmaf(xr[32 + k], WencK[k * 32 + j], acc);
        hK[(size_t)n * 32 + j] = acc;
    } else if (f < 64) {
        float acc = bencP1[j];
        #pragma unroll
        for (int k = 0; k < 32; k++) acc = fmaf(xr[k], WencP1[k * 32 + j], acc);
        h1[(size_t)n * 32 + j] = acc;
    } else if (f < 96) {
        float acc = bencP2[j];
        #pragma unroll
        for (int k = 0; k < 32; k++) acc = fmaf(xr[k], WencP2[k * 32 + j], acc);
        h2[(size_t)n * 32 + j] = acc;
    } else {
        float acc = bD[32 + j];
        #pragma unroll
        for (int k = 0; k < 64; k++) acc = fmaf(xr[k], WD[k * 64 + 32 + j], acc);
        DxU[(size_t)n * 32 + j] = acc;
    }
}

// K2: edge scatter of hK and DxU into dst accumulators. thread = (edge, f<32).
__global__ void k2_scatter1(const int* __restrict__ src, const int* __restrict__ dst,
                            const float* __restrict__ hK, const float* __restrict__ DxU,
                            float* __restrict__ hK_agg, float* __restrict__ d_agg) {
    int tid = blockIdx.x * blockDim.x + threadIdx.x;
    int e = tid >> 5;
    int f = tid & 31;
    if (e >= EE) return;
    int s = src[e], d = dst[e];
    atomAddF(&hK_agg[(size_t)d * 32 + f], hK[(size_t)s * 32 + f]);
    atomAddF(&d_agg[(size_t)d * 32 + f], DxU[(size_t)s * 32 + f]);
}

// K3: E_node = mlp3(hK_agg). node-per-thread, fully unrolled f32 (small: 50k nodes).
__global__ void k3_node_mlp(const float* __restrict__ hK_agg,
                            const float* __restrict__ WK1, const float* __restrict__ bK1,
                            const float* __restrict__ WK2, const float* __restrict__ bK2,
                            const float* __restrict__ WK3, const float* __restrict__ bK3,
                            float* __restrict__ Enode) {
    int n = blockIdx.x * blockDim.x + threadIdx.x;
    if (n >= NN) return;
    float in[32];
    const float4* iv = reinterpret_cast<const float4*>(hK_agg + (size_t)n * 32);
    #pragma unroll
    for (int i = 0; i < 8; i++) {
        float4 v = iv[i];
        in[4 * i + 0] = v.x; in[4 * i + 1] = v.y; in[4 * i + 2] = v.z; in[4 * i + 3] = v.w;
    }
    float t1[64];
    #pragma unroll
    for (int j = 0; j < 64; j++) t1[j] = bK1[j];
    #pragma unroll
    for (int k = 0; k < 32; k++) {
        float s0 = in[k];
        #pragma unroll
        for (int j = 0; j < 64; j++) t1[j] = fmaf(s0, WK1[k * 64 + j], t1[j]);
    }
    #pragma unroll
    for (int j = 0; j < 64; j++) t1[j] = fast_tanh(t1[j]);
    float t2[64];
    #pragma unroll
    for (int j = 0; j < 64; j++) t2[j] = bK2[j];
    #pragma unroll
    for (int k = 0; k < 64; k++) {
        float s0 = t1[k];
        #pragma unroll
        for (int j = 0; j < 64; j++) t2[j] = fmaf(s0, WK2[k * 64 + j], t2[j]);
    }
    #pragma unroll
    for (int j = 0; j < 64; j++) t2[j] = fmaxf(t2[j], 0.f);
    float t3[64];
    #pragma unroll
    for (int j = 0; j < 64; j++) t3[j] = bK3[j];
    #pragma unroll
    for (int k = 0; k < 64; k++) {
        float s0 = t2[k];
        #pragma unroll
        for (int j = 0; j < 64; j++) t3[j] = fmaf(s0, WK3[k * 64 + j], t3[j]);
    }
    float4* ov = reinterpret_cast<float4*>(Enode + (size_t)n * 64);
    #pragma unroll
    for (int i = 0; i < 16; i++) {
        float4 v; v.x = t3[4 * i + 0]; v.y = t3[4 * i + 1]; v.z = t3[4 * i + 2]; v.w = t3[4 * i + 3];
        ov[i] = v;
    }
}

// K4 (MFMA): edge MLP on matrix cores. Each wave owns 16-edge tiles.
//   Layer l: D[16 edges x 16 out] = mfma_f32_16x16x32_bf16(A, B) per N-tile/K-chunk.
//   A frag: lane holds A[row=lane&15][k = 8*(lane>>4)+i]  (k-permutation cancels: A and B
//           fragments are built with the SAME k mapping, so any HW k-order is correct).
//   D frag (m89-verified): col=lane&15, row=(lane>>4)*4+reg.
//   Inter-layer transpose through wave-private LDS (stride 68 floats: 16B-aligned rows,
//   2-way bank aliasing only). No __syncthreads needed (same-wave DS ops are in-order).
__global__ void __launch_bounds__(256) k4_mfma(
    const int* __restrict__ src, const int* __restrict__ dst,
    const float* __restrict__ h1, const float* __restrict__ h2,
    const float* __restrict__ Enode, float* __restrict__ Enew,
    const float* __restrict__ WU1, const float* __restrict__ bU1,
    const float* __restrict__ WU2, const float* __restrict__ bU2,
    const float* __restrict__ WU3, const float* __restrict__ bU3)
{
    __shared__ float xpose[4][16 * 68];
    const int wid  = threadIdx.x >> 6;
    const int lane = threadIdx.x & 63;
    const int g = lane >> 4;   // k-group 0..3
    const int r = lane & 15;   // A-row / D-col selector
    float* xp = xpose[wid];

    // ---- loop-invariant weight fragments (VGPR-resident) ----
    bf16x8 b1[4];            // W1: [32][64]
    #pragma unroll
    for (int nt = 0; nt < 4; nt++) {
        #pragma unroll
        for (int i = 0; i < 8; i++)
            b1[nt][i] = f2b(WU1[(g * 8 + i) * 64 + nt * 16 + r]);
    }
    bf16x8 b2[2][4], b3[2][4];  // W2,W3: [64][64], 2 K-chunks
    #pragma unroll
    for (int c = 0; c < 2; c++) {
        #pragma unroll
        for (int nt = 0; nt < 4; nt++) {
            #pragma unroll
            for (int i = 0; i < 8; i++) {
                b2[c][nt][i] = f2b(WU2[(c * 32 + g * 8 + i) * 64 + nt * 16 + r]);
                b3[c][nt][i] = f2b(WU3[(c * 32 + g * 8 + i) * 64 + nt * 16 + r]);
            }
        }
    }
    float bias1[4], bias2[4], bias3[4];
    #pragma unroll
    for (int nt = 0; nt < 4; nt++) {
        bias1[nt] = bU1[nt * 16 + r];
        bias2[nt] = bU2[nt * 16 + r];
        bias3[nt] = bU3[nt * 16 + r];
    }

    const int ntiles = EE / 16;                 // 50000, exact
    const int wave = blockIdx.x * 4 + wid;
    const int nw = gridDim.x * 4;
    const f32x4 zero = {0.f, 0.f, 0.f, 0.f};

    for (int tile = wave; tile < ntiles; tile += nw) {
        const int e0 = tile * 16;
        const int s_me = src[e0 + r];
        const int d_me = dst[e0 + r];

        // ---- layer 1: A = e_out[16 x 32] built straight from gathers ----
        bf16x8 a;
        {
            const float* p1 = h1 + (size_t)s_me * 32 + g * 8;
            const float* p2 = h2 + (size_t)d_me * 32 + g * 8;
            float4 x0 = *reinterpret_cast<const float4*>(p1);
            float4 x1 = *reinterpret_cast<const float4*>(p1 + 4);
            float4 y0 = *reinterpret_cast<const float4*>(p2);
            float4 y1 = *reinterpret_cast<const float4*>(p2 + 4);
            a[0] = f2b(x0.x + y0.x); a[1] = f2b(x0.y + y0.y);
            a[2] = f2b(x0.z + y0.z); a[3] = f2b(x0.w + y0.w);
            a[4] = f2b(x1.x + y1.x); a[5] = f2b(x1.y + y1.y);
            a[6] = f2b(x1.z + y1.z); a[7] = f2b(x1.w + y1.w);
        }
        f32x4 acc[4];
        #pragma unroll
        for (int nt = 0; nt < 4; nt++)
            acc[nt] = __builtin_amdgcn_mfma_f32_16x16x32_bf16(a, b1[nt], zero, 0, 0, 0);

        // tanh + bias, write transposed: row=edge=(g*4+q), col=nt*16+r
        #pragma unroll
        for (int nt = 0; nt < 4; nt++) {
            #pragma unroll
            for (int q = 0; q < 4; q++)
                xp[(g * 4 + q) * 68 + nt * 16 + r] = fast_tanh(acc[nt][q] + bias1[nt]);
        }

        // ---- layer 2 ----
        f32x4 acc2[4] = {zero, zero, zero, zero};
        #pragma unroll
        for (int c = 0; c < 2; c++) {
            const float* row = xp + r * 68 + c * 32 + g * 8;
            bf16x8 af;
            #pragma unroll
            for (int i = 0; i < 8; i++) af[i] = f2b(row[i]);
            #pragma unroll
            for (int nt = 0; nt < 4; nt++)
                acc2[nt] = __builtin_amdgcn_mfma_f32_16x16x32_bf16(af, b2[c][nt], acc2[nt], 0, 0, 0);
        }
        #pragma unroll
        for (int nt = 0; nt < 4; nt++) {
            #pragma unroll
            for (int q = 0; q < 4; q++)
                xp[(g * 4 + q) * 68 + nt * 16 + r] = fmaxf(acc2[nt][q] + bias2[nt], 0.f);
        }

        // ---- layer 3 ----
        f32x4 acc3[4] = {zero, zero, zero, zero};
        #pragma unroll
        for (int c = 0; c < 2; c++) {
            const float* row = xp + r * 68 + c * 32 + g * 8;
            bf16x8 af;
            #pragma unroll
            for (int i = 0; i < 8; i++) af[i] = f2b(row[i]);
            #pragma unroll
            for (int nt = 0; nt < 4; nt++)
                acc3[nt] = __builtin_amdgcn_mfma_f32_16x16x32_bf16(af, b3[c][nt], acc3[nt], 0, 0, 0);
        }

        // ---- E_new scatter: lane covers edge=g*4+q, col=nt*16+r ----
        #pragma unroll
        for (int q = 0; q < 4; q++) {
            const int er = g * 4 + q;
            const int ss = __shfl(s_me, er);
            const int dd = __shfl(d_me, er);
            const float* en = Enode + (size_t)ss * 64 + r;
            float* ew = Enew + (size_t)dd * 64 + r;
            #pragma unroll
            for (int nt = 0; nt < 4; nt++) {
                float v = (acc3[nt][q] + bias3[nt]) * en[nt * 16];
                atomAddF(ew + nt * 16, v);
            }
        }
    }
}

// K5: dH = E_new @ WH + bH ; out[:, :32] = dH[:,32:], out[:,32:] = -dH[:,:32] - d_agg
__global__ void k5_out(const float* __restrict__ Enew, const float* __restrict__ d_agg,
                       const float* __restrict__ WH, const float* __restrict__ bH,
                       float* __restrict__ out) {
    int tid = blockIdx.x * blockDim.x + threadIdx.x;
    int n = tid >> 6;
    int j = tid & 63;
    if (n >= NN) return;
    const float* er = Enew + (size_t)n * 64;
    int jj = (j < 32) ? (j + 32) : (j - 32);
    float acc = bH[jj];
    #pragma unroll
    for (int k = 0; k < 64; k++) acc = fmaf(er[k], WH[k * 64 + jj], acc);
    float val;
    if (j < 32) {
        val = acc;
    } else {
        val = -acc - d_agg[(size_t)n * 32 + (j - 32)];
    }
    out[tid] = val;
}

extern "C" void kernel_launch(void* const* d_in, const int* in_sizes, int n_in,
                              void* d_out, int out_size, void* d_ws, size_t ws_size,
                              hipStream_t stream) {
    const float* x      = (const float*)d_in[0];
    const int*   src    = (const int*)d_in[1];
    const int*   dst    = (const int*)d_in[2];
    const float* WencK  = (const float*)d_in[3];
    const float* bencK  = (const float*)d_in[4];
    const float* WencP1 = (const float*)d_in[5];
    const float* bencP1 = (const float*)d_in[6];
    const float* WencP2 = (const float*)d_in[7];
    const float* bencP2 = (const float*)d_in[8];
    const float* WK1    = (const float*)d_in[9];
    const float* bK1    = (const float*)d_in[10];
    const float* WK2    = (const float*)d_in[11];
    const float* bK2    = (const float*)d_in[12];
    const float* WK3    = (const float*)d_in[13];
    const float* bK3    = (const float*)d_in[14];
    const float* WU1    = (const float*)d_in[15];
    const float* bU1    = (const float*)d_in[16];
    const float* WU2    = (const float*)d_in[17];
    const float* bU2    = (const float*)d_in[18];
    const float* WU3    = (const float*)d_in[19];
    const float* bU3    = (const float*)d_in[20];
    const float* WH     = (const float*)d_in[21];
    const float* bH     = (const float*)d_in[22];
    const float* WD     = (const float*)d_in[23];
    const float* bD     = (const float*)d_in[24];
    float* out = (float*)d_out;

    float* ws = (float*)d_ws;
    // layout (floats): [hK_agg N*32 | d_agg N*32 | Enew N*64 | hK N*32 | h1 N*32 | h2 N*32 | DxU N*32 | Enode N*64]
    float* hK_agg = ws;
    float* d_agg  = ws + (size_t)NN * 32;
    float* Enew   = ws + (size_t)NN * 64;
    float* hK     = ws + (size_t)NN * 128;
    float* h1     = ws + (size_t)NN * 160;
    float* h2     = ws + (size_t)NN * 192;
    float* DxU    = ws + (size_t)NN * 224;
    float* Enode  = ws + (size_t)NN * 256;   // ends at NN*320 floats = 64 MB
    if (ws_size < (size_t)NN * 320 * sizeof(float)) return;

    // zero the three accumulators (contiguous, N*128 floats)
    hipMemsetAsync(ws, 0, (size_t)NN * 128 * sizeof(float), stream);

    k1_encoders<<<(NN * 128 + 255) / 256, 256, 0, stream>>>(
        x, WencK, bencK, WencP1, bencP1, WencP2, bencP2, WD, bD, hK, h1, h2, DxU);
    k2_scatter1<<<(EE * 32 + 255) / 256, 256, 0, stream>>>(src, dst, hK, DxU, hK_agg, d_agg);
    k3_node_mlp<<<(NN + 63) / 64, 64, 0, stream>>>(hK_agg, WK1, bK1, WK2, bK2, WK3, bK3, Enode);
    k4_mfma<<<2048, 256, 0, stream>>>(src, dst, h1, h2, Enode, Enew, WU1, bU1, WU2, bU2, WU3, bU3);
    k5_out<<<(NN * 64 + 255) / 256, 256, 0, stream>>>(Enew, d_agg, WH, bH, out);
}